// Round 2
// baseline (5024.211 us; speedup 1.0000x reference)
//
#include <hip/hip_runtime.h>
#include <math.h>

#define T_LEN 4096
#define D_DIM 1024
#define B_DIM 4
#define N_STAGES 3

typedef unsigned short bf16_t;

// ---------------------------------------------------------------- bf16 helpers
__device__ __forceinline__ bf16_t f2bf(float f) {
    union { float f; unsigned u; } v; v.f = f;
    unsigned r = v.u + 0x7FFFu + ((v.u >> 16) & 1u);   // round-nearest-even
    return (bf16_t)(r >> 16);
}
__device__ __forceinline__ float bf2f(bf16_t h) {
    union { unsigned u; float f; } v; v.u = ((unsigned)h) << 16;
    return v.f;
}

__device__ __forceinline__ float2 cmul(float2 a, float2 b) {
    return make_float2(a.x * b.x - a.y * b.y, a.x * b.y + a.y * b.x);
}

// ---------------------------------------------------------------- pos encoding
__global__ __launch_bounds__(256) void pos_kernel(float* __restrict__ pos) {
    int idx = blockIdx.x * 256 + threadIdx.x;           // T_LEN * D_DIM total
    int t = idx >> 10;
    int k = idx & 1023;
    float e = (float)(k & ~1) / (float)D_DIM;
    float r = exp2f(-e * 13.287712379549449f);          // 10000^-e
    float angle = (float)t * r;
    pos[idx] = (k & 1) ? cosf(angle) : sinf(angle);
}

// ---------------------------------------------------------------- f32 SGEMM
// C[M,N] = A[M,K] @ W[K,N] + bias[N], transposed scatter-store epilogue.
// MODE 0: bf16 out, index = ((s*4 + b)*1024 + d)*4096 + t  (s=c>>10,d=c&1023,b=r>>12,t=r&4095)
// MODE 1: f32 out,  index = c*4096 + r
#define BM 128
#define BN 128
#define BK 16
template <int MODE>
__global__ __launch_bounds__(256) void sgemm_kernel(const float* __restrict__ A,
                                                    const float* __restrict__ W,
                                                    const float* __restrict__ bias,
                                                    void* __restrict__ outv,
                                                    int M, int N, int K) {
    __shared__ float As[BK][BM];
    __shared__ float Bs[BK][BN];
    const int tid = threadIdx.x;
    const int row0 = blockIdx.y * BM;
    const int col0 = blockIdx.x * BN;
    const int tm = tid >> 4;   // 0..15
    const int tn = tid & 15;   // 0..15

    float acc[8][8];
#pragma unroll
    for (int i = 0; i < 8; ++i)
#pragma unroll
        for (int j = 0; j < 8; ++j) acc[i][j] = 0.0f;

    for (int k0 = 0; k0 < K; k0 += BK) {
#pragma unroll
        for (int i = 0; i < 2; ++i) {
            int idx = tid + 256 * i;
            int r = idx >> 2;
            int c4 = idx & 3;
            float4 v = *(const float4*)&A[(size_t)(row0 + r) * K + k0 + c4 * 4];
            As[c4 * 4 + 0][r] = v.x;
            As[c4 * 4 + 1][r] = v.y;
            As[c4 * 4 + 2][r] = v.z;
            As[c4 * 4 + 3][r] = v.w;
        }
#pragma unroll
        for (int i = 0; i < 2; ++i) {
            int idx = tid + 256 * i;
            int r = idx >> 5;
            int c4 = idx & 31;
            float4 v = *(const float4*)&W[(size_t)(k0 + r) * N + col0 + c4 * 4];
            *(float4*)&Bs[r][c4 * 4] = v;
        }
        __syncthreads();
#pragma unroll
        for (int kk = 0; kk < BK; ++kk) {
            float a[8], b[8];
            *(float4*)&a[0] = *(const float4*)&As[kk][tm * 8];
            *(float4*)&a[4] = *(const float4*)&As[kk][tm * 8 + 4];
            *(float4*)&b[0] = *(const float4*)&Bs[kk][tn * 8];
            *(float4*)&b[4] = *(const float4*)&Bs[kk][tn * 8 + 4];
#pragma unroll
            for (int i = 0; i < 8; ++i)
#pragma unroll
                for (int j = 0; j < 8; ++j) acc[i][j] += a[i] * b[j];
        }
        __syncthreads();
    }

#pragma unroll
    for (int i = 0; i < 8; ++i) {
        int r = row0 + tm * 8 + i;
#pragma unroll
        for (int j = 0; j < 8; ++j) {
            int c = col0 + tn * 8 + j;
            float v = acc[i][j] + bias[c];
            if (MODE == 0) {
                int s = c >> 10, d = c & 1023;
                int b = r >> 12, t = r & 4095;
                ((bf16_t*)outv)[((size_t)(s * 4 + b) * 1024 + d) * 4096 + t] = f2bf(v);
            } else {
                ((float*)outv)[(size_t)c * 4096 + r] = v;
            }
        }
    }
}

// ---------------------------------------------------------------- Stockham FFT (radix-2, N=8192)
// Wt[x] = exp(-i*pi*x/4096) for x in [0,2048); [2048,4096) via *(-i) folding.
// Result always lands in bufOut (13 passes).
__device__ void fft8192(float2* bufIn, float2* bufOut, const float2* __restrict__ Wt, int inv) {
    const int tid = threadIdx.x;
    float2* src = bufIn;
    float2* dst = bufOut;
    int m = 1;
    for (int stage = 0; stage < 13; ++stage) {
#pragma unroll 4
        for (int u = 0; u < 16; ++u) {
            int p = u * 256 + tid;
            int jm = p & ~(m - 1);
            float2 c0 = src[p];
            float2 c1 = src[p + 4096];
            float2 w = Wt[jm & 2047];
            if (jm & 2048) { float tw = w.x; w.x = w.y; w.y = -tw; }  // * (-i)
            if (inv) w.y = -w.y;
            float2 sum = make_float2(c0.x + c1.x, c0.y + c1.y);
            float2 dif = make_float2(c0.x - c1.x, c0.y - c1.y);
            dst[p + jm] = sum;
            dst[p + jm + m] = cmul(w, dif);
        }
        __syncthreads();
        float2* t = src; src = dst; dst = t;
        m <<= 1;
    }
}

__device__ __forceinline__ void init_twiddles(float2* Wt) {
    const int tid = threadIdx.x;
#pragma unroll
    for (int u = 0; u < 8; ++u) {
        int j = u * 256 + tid;
        float s, c;
        __sincosf(-3.14159265358979323846f * (float)j / 4096.0f, &s, &c);
        Wt[j] = make_float2(c, s);
    }
}

// ---------------------------------------------------------------- filter spectra
// fT: [(i*D+d)][t] f32; spectra half-spectrum k in [0,4096], row stride 4097
__global__ __launch_bounds__(256) void filter_fft_kernel(const float* __restrict__ fT,
                                                          void* __restrict__ specv,
                                                          int spec_bf16) {
    __shared__ float2 bufA[8192];
    __shared__ float2 bufB[8192];
    __shared__ float2 Wt[2048];
    const int tid = threadIdx.x;
    const int bid = blockIdx.x;  // i*1024 + d
    init_twiddles(Wt);
    const float* f = &fT[(size_t)bid * T_LEN];
#pragma unroll
    for (int u = 0; u < 16; ++u) {
        int t = u * 256 + tid;
        bufA[t] = make_float2(f[t], 0.0f);
        bufA[t + 4096] = make_float2(0.0f, 0.0f);
    }
    __syncthreads();
    fft8192(bufA, bufB, Wt, 0);
    if (spec_bf16) {
        ushort2* outp = (ushort2*)specv + (size_t)bid * 4097;
        for (int u = 0; u < 17; ++u) {
            int k = u * 256 + tid;
            if (k <= 4096) outp[k] = make_ushort2(f2bf(bufB[k].x), f2bf(bufB[k].y));
        }
    } else {
        float2* outp = (float2*)specv + (size_t)bid * 4097;
        for (int u = 0; u < 17; ++u) {
            int k = u * 256 + tid;
            if (k <= 4096) outp[k] = bufB[k];
        }
    }
}

// ---------------------------------------------------------------- fused 3-stage conv
// xpT (bf16): ((s*4 + b)*1024 + d)*4096 + t ; writes out (B,T,D) f32 directly
__global__ __launch_bounds__(256) void conv_kernel(const bf16_t* __restrict__ xpT,
                                                   const void* __restrict__ specv,
                                                   int spec_bf16,
                                                   float* __restrict__ out) {
    __shared__ float2 bufA[8192];
    __shared__ float2 bufB[8192];
    __shared__ float2 Wt[2048];
    const int tid = threadIdx.x;
    const int bid = blockIdx.x;        // b*1024 + d
    const int b = bid >> 10;
    const int d = bid & 1023;
    init_twiddles(Wt);

    const bf16_t* y0 = &xpT[((size_t)b * 1024 + d) * T_LEN];
#pragma unroll
    for (int u = 0; u < 16; ++u) {
        int t = u * 256 + tid;
        bufA[t] = make_float2(bf2f(y0[t]), 0.0f);
        bufA[t + 4096] = make_float2(0.0f, 0.0f);
    }
    __syncthreads();

    const float scale = 1.0f / 8192.0f;
    for (int st = 0; st < N_STAGES; ++st) {
        fft8192(bufA, bufB, Wt, 0);    // forward -> bufB
        // pointwise multiply (Hermitian reconstruction from half-spectrum)
        for (int u = 0; u < 32; ++u) {
            int k = u * 256 + tid;
            int src_k = (k <= 4096) ? k : 8192 - k;
            float2 Fk;
            if (spec_bf16) {
                ushort2 h = ((const ushort2*)specv)[(size_t)(st * 1024 + d) * 4097 + src_k];
                Fk = make_float2(bf2f(h.x), bf2f(h.y));
            } else {
                Fk = ((const float2*)specv)[(size_t)(st * 1024 + d) * 4097 + src_k];
            }
            if (k > 4096) Fk.y = -Fk.y;
            bufB[k] = cmul(bufB[k], Fk);
        }
        __syncthreads();
        fft8192(bufB, bufA, Wt, 1);    // inverse -> bufA

        const bf16_t* g = &xpT[((size_t)((st + 1) * 4 + b) * 1024 + d) * T_LEN];
        if (st < N_STAGES - 1) {
#pragma unroll
            for (int u = 0; u < 16; ++u) {
                int t = u * 256 + tid;
                float v = bufA[t].x * scale * bf2f(g[t]);
                bufA[t] = make_float2(v, 0.0f);
                bufA[t + 4096] = make_float2(0.0f, 0.0f);
            }
            __syncthreads();
        } else {
            // final stage: gate and scatter straight to out (B,T,D)
#pragma unroll
            for (int u = 0; u < 16; ++u) {
                int t = u * 256 + tid;
                float v = bufA[t].x * scale * bf2f(g[t]);
                out[((size_t)b * 4096 + t) * 1024 + d] = v;
            }
        }
    }
}

// ---------------------------------------------------------------- launch
extern "C" void kernel_launch(void* const* d_in, const int* in_sizes, int n_in,
                              void* d_out, int out_size, void* d_ws, size_t ws_size,
                              hipStream_t stream) {
    const float* X  = (const float*)d_in[0];
    const float* Wp = (const float*)d_in[1];
    const float* bp = (const float*)d_in[2];
    const float* Wf = (const float*)d_in[3];
    const float* bf = (const float*)d_in[4];
    float* out = (float*)d_out;
    char* ws = (char*)d_ws;

    // workspace layout (compact, ws-adaptive):
    //  [0, 128Mi)          xpT bf16 (4 stages, B, D, T). Before GEMM2 runs, this
    //                      region stages pos f32 [0,16Mi) and fT f32 [16Mi,64Mi).
    //  [128Mi, ...)        filter spectra: 3*1024 rows x 4097 complex,
    //                      f32 pairs if ws allows (100.7MB), else bf16 pairs (50.3MB)
    const size_t XPT_BYTES = (size_t)134217728;
    const size_t SPEC_F32_END  = XPT_BYTES + (size_t)3 * 1024 * 4097 * 8;
    bf16_t* xpT  = (bf16_t*)ws;
    float*  pos  = (float*)ws;
    float*  fT   = (float*)(ws + 16777216);
    void*   spec = (void*)(ws + XPT_BYTES);
    int spec_bf16 = (ws_size >= SPEC_F32_END) ? 0 : 1;

    // 1. positional encoding
    pos_kernel<<<(T_LEN * D_DIM) / 256, 256, 0, stream>>>(pos);

    // 2. f = pos @ Wf + bf  -> fT[(i*D+d)][t]  (f32)
    sgemm_kernel<1><<<dim3(3072 / BN, 4096 / BM), 256, 0, stream>>>(
        pos, Wf, bf, fT, 4096, 3072, 1024);

    // 3. filter spectra
    filter_fft_kernel<<<N_STAGES * D_DIM, 256, 0, stream>>>(fT, spec, spec_bf16);

    // 4. xp = X @ Wp + bp -> xpT bf16 (overwrites pos/fT staging)
    sgemm_kernel<0><<<dim3(4096 / BN, 16384 / BM), 256, 0, stream>>>(
        X, Wp, bp, xpT, 16384, 4096, 1024);

    // 5. fused 3-stage FFT conv + gating, final stage writes d_out directly
    conv_kernel<<<B_DIM * D_DIM, 256, 0, stream>>>(xpT, spec, spec_bf16, out);
}

// Round 3
// 2671.886 us; speedup vs baseline: 1.8804x; 1.8804x over previous
//
#include <hip/hip_runtime.h>
#include <math.h>

#define T_LEN 4096
#define D_DIM 1024
#define B_DIM 4
#define N_STAGES 3

typedef unsigned short bf16_t;
typedef __bf16 bf16x8 __attribute__((ext_vector_type(8)));
typedef float f32x4 __attribute__((ext_vector_type(4)));

// ---------------------------------------------------------------- bf16 helpers
__device__ __forceinline__ bf16_t f2bf(float f) {
    union { float f; unsigned u; } v; v.f = f;
    unsigned r = v.u + 0x7FFFu + ((v.u >> 16) & 1u);   // round-nearest-even
    return (bf16_t)(r >> 16);
}
__device__ __forceinline__ float bf2f(bf16_t h) {
    union { unsigned u; float f; } v; v.u = ((unsigned)h) << 16;
    return v.f;
}

__device__ __forceinline__ float2 cmul(float2 a, float2 b) {
    return make_float2(a.x * b.x - a.y * b.y, a.x * b.y + a.y * b.x);
}

#define GLOAD_LDS16(gp, lp) __builtin_amdgcn_global_load_lds( \
    (const __attribute__((address_space(1))) void*)(gp),      \
    (__attribute__((address_space(3))) void*)(lp), 16, 0, 0)

// ---------------------------------------------------------------- pos encoding (bf16 out)
__global__ __launch_bounds__(256) void pos_kernel(bf16_t* __restrict__ posbf) {
    int idx = blockIdx.x * 256 + threadIdx.x;           // T_LEN * D_DIM total
    int t = idx >> 10;
    int k = idx & 1023;
    float e = (float)(k & ~1) / (float)D_DIM;
    float r = exp2f(-e * 13.287712379549449f);          // 10000^-e
    float angle = (float)t * r;
    float v = (k & 1) ? cosf(angle) : sinf(angle);
    posbf[idx] = f2bf(v);
}

// ---------------------------------------------------------------- f32 -> bf16 copy (8/thread)
__global__ __launch_bounds__(256) void f32_to_bf16_kernel(const float* __restrict__ in,
                                                          bf16_t* __restrict__ out, int n8) {
    int i = blockIdx.x * 256 + threadIdx.x;
    if (i >= n8) return;
    float4 a = ((const float4*)in)[i * 2];
    float4 b = ((const float4*)in)[i * 2 + 1];
    ushort4 lo = make_ushort4(f2bf(a.x), f2bf(a.y), f2bf(a.z), f2bf(a.w));
    ushort4 hi = make_ushort4(f2bf(b.x), f2bf(b.y), f2bf(b.z), f2bf(b.w));
    ((ushort4*)out)[i * 2] = lo;
    ((ushort4*)out)[i * 2 + 1] = hi;
}

// ---------------------------------------------------------------- W [K][N] f32 -> WT [N][K] bf16
__global__ __launch_bounds__(256) void transpose_to_bf16(const float* __restrict__ in,
                                                         bf16_t* __restrict__ out, int K, int N) {
    __shared__ float tile[32][33];
    const int n0 = blockIdx.x * 32;
    const int k0 = blockIdx.y * 32;
    const int tx = threadIdx.x & 31;
    const int ty = threadIdx.x >> 5;  // 0..7
    for (int i = ty; i < 32; i += 8)
        tile[i][tx] = in[(size_t)(k0 + i) * N + n0 + tx];
    __syncthreads();
    for (int i = ty; i < 32; i += 8)
        out[(size_t)(n0 + i) * K + k0 + tx] = f2bf(tile[tx][i]);
}

// ---------------------------------------------------------------- bf16 MFMA GEMM (m97 structure)
// C[M,N] = A[M,K](bf16) @ BT[N,K](bf16)^T + bias(f32); 128x128 tile, BK=32, 4 waves.
// MODE 0: bf16 out, idx = ((s*4+b)*1024+d)*4096 + t  (s=c>>10,d=c&1023,b=r>>12,t=r&4095)
// MODE 1: f32 out,  idx = c*4096 + r
template <int MODE>
__global__ __launch_bounds__(256) void mfma_gemm(const bf16_t* __restrict__ A,
                                                 const bf16_t* __restrict__ BT,
                                                 const float* __restrict__ bias,
                                                 void* __restrict__ outv,
                                                 int M, int N, int K, int nbx) {
    constexpr int SMEM_BYTES = (MODE == 0) ? (128 * 136 * 2) : (128 * 132 * 4);
    __shared__ __align__(16) char smem[SMEM_BYTES];
    bf16_t* As = (bf16_t*)smem;               // [128][32] linear, 8192 B
    bf16_t* Bs = (bf16_t*)(smem + 8192);      // [128][32] linear, 8192 B

    const int tid = threadIdx.x;
    const int lane = tid & 63;
    const int w = tid >> 6;                   // wave 0..3
    const int wr = w >> 1, wc = w & 1;

    // XCD-aware swizzle (grid divisible by 8)
    const int nwg = gridDim.x;
    const int q = nwg >> 3;
    const int swz = (blockIdx.x & 7) * q + (blockIdx.x >> 3);
    const int by = swz / nbx, bx = swz - by * nbx;
    const int row0 = by * 128, col0 = bx * 128;

    f32x4 acc[4][4];
#pragma unroll
    for (int m = 0; m < 4; ++m)
#pragma unroll
        for (int n = 0; n < 4; ++n) acc[m][n] = (f32x4)(0.0f);

    // per-lane staging geometry: chunk byte-offset = (w*2+c)*1024 + lane*16
    int offs[2], rr[2], kk8[2];
#pragma unroll
    for (int c = 0; c < 2; ++c) {
        offs[c] = (w * 2 + c) * 1024 + lane * 16;
        rr[c] = offs[c] >> 6;                 // row in tile (64 B per row)
        kk8[c] = ((offs[c] >> 4) & 3) * 8;    // element offset in row
    }

    for (int k0 = 0; k0 < K; k0 += 32) {
#pragma unroll
        for (int c = 0; c < 2; ++c) {
            const bf16_t* gA = A + (size_t)(row0 + rr[c]) * K + k0 + kk8[c];
            GLOAD_LDS16(gA, As + (w * 2 + c) * 512);
            const bf16_t* gB = BT + (size_t)(col0 + rr[c]) * K + k0 + kk8[c];
            GLOAD_LDS16(gB, Bs + (w * 2 + c) * 512);
        }
        __syncthreads();   // drains vmcnt before ds_read

        bf16x8 af[4], bfr[4];
#pragma unroll
        for (int m = 0; m < 4; ++m)
            af[m] = *(const bf16x8*)&As[(wr * 64 + m * 16 + (lane & 15)) * 32 + (lane >> 4) * 8];
#pragma unroll
        for (int n = 0; n < 4; ++n)
            bfr[n] = *(const bf16x8*)&Bs[(wc * 64 + n * 16 + (lane & 15)) * 32 + (lane >> 4) * 8];
#pragma unroll
        for (int m = 0; m < 4; ++m)
#pragma unroll
            for (int n = 0; n < 4; ++n)
                acc[m][n] = __builtin_amdgcn_mfma_f32_16x16x32_bf16(af[m], bfr[n], acc[m][n], 0, 0, 0);
        __syncthreads();   // protect LDS before next stage
    }

    // ---------------- epilogue: LDS transpose staging for coalesced stores
    if (MODE == 0) {
        bf16_t* Cs = (bf16_t*)smem;           // [128 cols][pitch 136]
#pragma unroll
        for (int m = 0; m < 4; ++m)
#pragma unroll
            for (int n = 0; n < 4; ++n) {
                int cl = wc * 64 + n * 16 + (lane & 15);
                int rlb = wr * 64 + m * 16 + ((lane >> 4) << 2);
                float bb = bias[col0 + cl];
#pragma unroll
                for (int j = 0; j < 4; ++j)
                    Cs[cl * 136 + rlb + j] = f2bf(acc[m][n][j] + bb);
            }
        __syncthreads();
        int dl = tid >> 1, th = tid & 1;
        int cc = col0 + dl;
        int s = cc >> 10, d = cc & 1023;
        int b = row0 >> 12;
        int t0 = (row0 & 4095) + th * 64;
        uint4* dst = (uint4*)&((bf16_t*)outv)[((size_t)(s * 4 + b) * 1024 + d) * 4096 + t0];
        const uint4* src = (const uint4*)&Cs[dl * 136 + th * 64];
#pragma unroll
        for (int j = 0; j < 8; ++j) dst[j] = src[j];
    } else {
        float* CsF = (float*)smem;            // [128 cols][pitch 132]
#pragma unroll
        for (int m = 0; m < 4; ++m)
#pragma unroll
            for (int n = 0; n < 4; ++n) {
                int cl = wc * 64 + n * 16 + (lane & 15);
                int rlb = wr * 64 + m * 16 + ((lane >> 4) << 2);
                float bb = bias[col0 + cl];
#pragma unroll
                for (int j = 0; j < 4; ++j)
                    CsF[cl * 132 + rlb + j] = acc[m][n][j] + bb;
            }
        __syncthreads();
        int dl = tid >> 1, th = tid & 1;
        int cc = col0 + dl;
        uint4* dst = (uint4*)&((float*)outv)[(size_t)cc * 4096 + row0 + th * 64];
        const uint4* src = (const uint4*)&CsF[dl * 132 + th * 64];
#pragma unroll
        for (int j = 0; j < 16; ++j) dst[j] = src[j];
    }
}

// ---------------------------------------------------------------- Stockham FFT (radix-2, N=8192)
__device__ void fft8192(float2* bufIn, float2* bufOut, const float2* __restrict__ Wt, int inv) {
    const int tid = threadIdx.x;
    float2* src = bufIn;
    float2* dst = bufOut;
    int m = 1;
    for (int stage = 0; stage < 13; ++stage) {
#pragma unroll 4
        for (int u = 0; u < 16; ++u) {
            int p = u * 256 + tid;
            int jm = p & ~(m - 1);
            float2 c0 = src[p];
            float2 c1 = src[p + 4096];
            float2 w = Wt[jm & 2047];
            if (jm & 2048) { float tw = w.x; w.x = w.y; w.y = -tw; }  // * (-i)
            if (inv) w.y = -w.y;
            float2 sum = make_float2(c0.x + c1.x, c0.y + c1.y);
            float2 dif = make_float2(c0.x - c1.x, c0.y - c1.y);
            dst[p + jm] = sum;
            dst[p + jm + m] = cmul(w, dif);
        }
        __syncthreads();
        float2* t = src; src = dst; dst = t;
        m <<= 1;
    }
}

__device__ __forceinline__ void init_twiddles(float2* Wt) {
    const int tid = threadIdx.x;
#pragma unroll
    for (int u = 0; u < 8; ++u) {
        int j = u * 256 + tid;
        float s, c;
        __sincosf(-3.14159265358979323846f * (float)j / 4096.0f, &s, &c);
        Wt[j] = make_float2(c, s);
    }
}

// ---------------------------------------------------------------- filter spectra
__global__ __launch_bounds__(256) void filter_fft_kernel(const float* __restrict__ fT,
                                                          void* __restrict__ specv,
                                                          int spec_bf16) {
    __shared__ float2 bufA[8192];
    __shared__ float2 bufB[8192];
    __shared__ float2 Wt[2048];
    const int tid = threadIdx.x;
    const int bid = blockIdx.x;  // i*1024 + d
    init_twiddles(Wt);
    const float* f = &fT[(size_t)bid * T_LEN];
#pragma unroll
    for (int u = 0; u < 16; ++u) {
        int t = u * 256 + tid;
        bufA[t] = make_float2(f[t], 0.0f);
        bufA[t + 4096] = make_float2(0.0f, 0.0f);
    }
    __syncthreads();
    fft8192(bufA, bufB, Wt, 0);
    if (spec_bf16) {
        ushort2* outp = (ushort2*)specv + (size_t)bid * 4097;
        for (int u = 0; u < 17; ++u) {
            int k = u * 256 + tid;
            if (k <= 4096) outp[k] = make_ushort2(f2bf(bufB[k].x), f2bf(bufB[k].y));
        }
    } else {
        float2* outp = (float2*)specv + (size_t)bid * 4097;
        for (int u = 0; u < 17; ++u) {
            int k = u * 256 + tid;
            if (k <= 4096) outp[k] = bufB[k];
        }
    }
}

// ---------------------------------------------------------------- fused 3-stage conv
__global__ __launch_bounds__(256) void conv_kernel(const bf16_t* __restrict__ xpT,
                                                   const void* __restrict__ specv,
                                                   int spec_bf16,
                                                   float* __restrict__ out) {
    __shared__ float2 bufA[8192];
    __shared__ float2 bufB[8192];
    __shared__ float2 Wt[2048];
    const int tid = threadIdx.x;
    const int bid = blockIdx.x;        // b*1024 + d
    const int b = bid >> 10;
    const int d = bid & 1023;
    init_twiddles(Wt);

    const bf16_t* y0 = &xpT[((size_t)b * 1024 + d) * T_LEN];
#pragma unroll
    for (int u = 0; u < 16; ++u) {
        int t = u * 256 + tid;
        bufA[t] = make_float2(bf2f(y0[t]), 0.0f);
        bufA[t + 4096] = make_float2(0.0f, 0.0f);
    }
    __syncthreads();

    const float scale = 1.0f / 8192.0f;
    for (int st = 0; st < N_STAGES; ++st) {
        fft8192(bufA, bufB, Wt, 0);    // forward -> bufB
        for (int u = 0; u < 32; ++u) {
            int k = u * 256 + tid;
            int src_k = (k <= 4096) ? k : 8192 - k;
            float2 Fk;
            if (spec_bf16) {
                ushort2 h = ((const ushort2*)specv)[(size_t)(st * 1024 + d) * 4097 + src_k];
                Fk = make_float2(bf2f(h.x), bf2f(h.y));
            } else {
                Fk = ((const float2*)specv)[(size_t)(st * 1024 + d) * 4097 + src_k];
            }
            if (k > 4096) Fk.y = -Fk.y;
            bufB[k] = cmul(bufB[k], Fk);
        }
        __syncthreads();
        fft8192(bufB, bufA, Wt, 1);    // inverse -> bufA

        const bf16_t* g = &xpT[((size_t)((st + 1) * 4 + b) * 1024 + d) * T_LEN];
        if (st < N_STAGES - 1) {
#pragma unroll
            for (int u = 0; u < 16; ++u) {
                int t = u * 256 + tid;
                float v = bufA[t].x * scale * bf2f(g[t]);
                bufA[t] = make_float2(v, 0.0f);
                bufA[t + 4096] = make_float2(0.0f, 0.0f);
            }
            __syncthreads();
        } else {
#pragma unroll
            for (int u = 0; u < 16; ++u) {
                int t = u * 256 + tid;
                float v = bufA[t].x * scale * bf2f(g[t]);
                out[((size_t)b * 4096 + t) * 1024 + d] = v;
            }
        }
    }
}

// ---------------------------------------------------------------- launch
extern "C" void kernel_launch(void* const* d_in, const int* in_sizes, int n_in,
                              void* d_out, int out_size, void* d_ws, size_t ws_size,
                              hipStream_t stream) {
    const float* X   = (const float*)d_in[0];
    const float* Wp  = (const float*)d_in[1];
    const float* bp  = (const float*)d_in[2];
    const float* Wf  = (const float*)d_in[3];
    const float* bfv = (const float*)d_in[4];
    float* out = (float*)d_out;
    char* ws = (char*)d_ws;

    // workspace:
    //  [0, 128Mi)  xpT bf16. Pre-GEMM staging inside: posbf [0,8Mi), WfT [16Mi,22Mi),
    //              fT f32 [32Mi,80Mi).
    //  [128Mi, +spec)       filter spectra (f32 pairs if ws allows, else bf16 pairs)
    //  [.., +32Mi)          Xbf  (bf16 copy of X)
    //  [.., +8Mi)           WpT  (bf16 transposed Wp)
    const size_t XPT_BYTES  = (size_t)134217728;
    const size_t SPEC_F32_B = (size_t)3 * 1024 * 4097 * 8;   // 100,687,872
    const size_t SPEC_BF_B  = (size_t)3 * 1024 * 4097 * 4;   //  50,343,936
    const size_t XBF_BYTES  = (size_t)33554432;
    const size_t WPT_BYTES  = (size_t)8388608;

    bf16_t* xpT   = (bf16_t*)ws;
    bf16_t* posbf = (bf16_t*)ws;
    bf16_t* WfT   = (bf16_t*)(ws + 16777216);
    float*  fT    = (float*)(ws + 33554432);
    void*   spec  = (void*)(ws + XPT_BYTES);

    int spec_bf16;
    size_t spec_bytes;
    if (ws_size >= XPT_BYTES + SPEC_F32_B + XBF_BYTES + WPT_BYTES) {
        spec_bf16 = 0; spec_bytes = SPEC_F32_B;
    } else {
        spec_bf16 = 1; spec_bytes = SPEC_BF_B;
    }
    bf16_t* Xbf = (bf16_t*)(ws + XPT_BYTES + spec_bytes);
    bf16_t* WpT = (bf16_t*)(ws + XPT_BYTES + spec_bytes + XBF_BYTES);

    // 1. positional encoding (bf16)
    pos_kernel<<<(T_LEN * D_DIM) / 256, 256, 0, stream>>>(posbf);

    // 2. WfT = transpose(Wf) bf16 ; f = pos @ Wf + bf -> fT f32 [(i*D+d)][t]
    transpose_to_bf16<<<dim3(3072 / 32, 1024 / 32), 256, 0, stream>>>(Wf, WfT, 1024, 3072);
    mfma_gemm<1><<<768, 256, 0, stream>>>(posbf, WfT, bfv, fT, 4096, 3072, 1024, 24);

    // 3. filter spectra
    filter_fft_kernel<<<N_STAGES * D_DIM, 256, 0, stream>>>(fT, spec, spec_bf16);

    // 4. Xbf, WpT ; xp = X @ Wp + bp -> xpT bf16 (overwrites staging in [0,128Mi))
    f32_to_bf16_kernel<<<8192, 256, 0, stream>>>(X, Xbf, 2097152);
    transpose_to_bf16<<<dim3(4096 / 32, 1024 / 32), 256, 0, stream>>>(Wp, WpT, 1024, 4096);
    mfma_gemm<0><<<4096, 256, 0, stream>>>(Xbf, WpT, bp, xpT, 16384, 4096, 1024, 32);

    // 5. fused 3-stage FFT conv + gating -> d_out
    conv_kernel<<<B_DIM * D_DIM, 256, 0, stream>>>(xpT, spec, spec_bf16, out);
}

// Round 4
// 905.097 us; speedup vs baseline: 5.5510x; 2.9520x over previous
//
#include <hip/hip_runtime.h>
#include <math.h>

#define T_LEN 4096
#define D_DIM 1024
#define B_DIM 4
#define N_STAGES 3
#define NT 512          // threads for FFT kernels

typedef unsigned short bf16_t;
typedef __bf16 bf16x8 __attribute__((ext_vector_type(8)));
typedef float f32x4 __attribute__((ext_vector_type(4)));

// ---------------------------------------------------------------- helpers
__device__ __forceinline__ bf16_t f2bf(float f) {
    union { float f; unsigned u; } v; v.f = f;
    unsigned r = v.u + 0x7FFFu + ((v.u >> 16) & 1u);   // round-nearest-even
    return (bf16_t)(r >> 16);
}
__device__ __forceinline__ float bf2f(bf16_t h) {
    union { unsigned u; float f; } v; v.u = ((unsigned)h) << 16;
    return v.f;
}
__device__ __forceinline__ float2 cmul(float2 a, float2 b) {
    return make_float2(a.x * b.x - a.y * b.y, a.x * b.y + a.y * b.x);
}
__device__ __forceinline__ float2 cadd(float2 a, float2 b) { return make_float2(a.x + b.x, a.y + b.y); }
__device__ __forceinline__ float2 csub(float2 a, float2 b) { return make_float2(a.x - b.x, a.y - b.y); }
__device__ __forceinline__ float2 conjf2(float2 a) { return make_float2(a.x, -a.y); }

#define GLOAD_LDS16(gp, lp) __builtin_amdgcn_global_load_lds( \
    (const __attribute__((address_space(1))) void*)(gp),      \
    (__attribute__((address_space(3))) void*)(lp), 16, 0, 0)

// ---------------------------------------------------------------- pos encoding (bf16 out)
__global__ __launch_bounds__(256) void pos_kernel(bf16_t* __restrict__ posbf) {
    int idx = blockIdx.x * 256 + threadIdx.x;
    int t = idx >> 10;
    int k = idx & 1023;
    float e = (float)(k & ~1) / (float)D_DIM;
    float r = exp2f(-e * 13.287712379549449f);          // 10000^-e
    float angle = (float)t * r;
    float v = (k & 1) ? cosf(angle) : sinf(angle);
    posbf[idx] = f2bf(v);
}

// ---------------------------------------------------------------- f32 -> bf16 copy
__global__ __launch_bounds__(256) void f32_to_bf16_kernel(const float* __restrict__ in,
                                                          bf16_t* __restrict__ out, int n8) {
    int i = blockIdx.x * 256 + threadIdx.x;
    if (i >= n8) return;
    float4 a = ((const float4*)in)[i * 2];
    float4 b = ((const float4*)in)[i * 2 + 1];
    ((ushort4*)out)[i * 2]     = make_ushort4(f2bf(a.x), f2bf(a.y), f2bf(a.z), f2bf(a.w));
    ((ushort4*)out)[i * 2 + 1] = make_ushort4(f2bf(b.x), f2bf(b.y), f2bf(b.z), f2bf(b.w));
}

// ---------------------------------------------------------------- W [K][N] f32 -> WT [N][K] bf16
__global__ __launch_bounds__(256) void transpose_to_bf16(const float* __restrict__ in,
                                                         bf16_t* __restrict__ out, int K, int N) {
    __shared__ float tile[32][33];
    const int n0 = blockIdx.x * 32;
    const int k0 = blockIdx.y * 32;
    const int tx = threadIdx.x & 31;
    const int ty = threadIdx.x >> 5;
    for (int i = ty; i < 32; i += 8)
        tile[i][tx] = in[(size_t)(k0 + i) * N + n0 + tx];
    __syncthreads();
    for (int i = ty; i < 32; i += 8)
        out[(size_t)(n0 + i) * K + k0 + tx] = f2bf(tile[tx][i]);
}

// ---------------------------------------------------------------- bf16 MFMA GEMM (m97 structure)
template <int MODE>
__global__ __launch_bounds__(256) void mfma_gemm(const bf16_t* __restrict__ A,
                                                 const bf16_t* __restrict__ BT,
                                                 const float* __restrict__ bias,
                                                 void* __restrict__ outv,
                                                 int M, int N, int K, int nbx) {
    constexpr int SMEM_BYTES = (MODE == 0) ? (128 * 136 * 2) : (128 * 132 * 4);
    __shared__ __align__(16) char smem[SMEM_BYTES];
    bf16_t* As = (bf16_t*)smem;
    bf16_t* Bs = (bf16_t*)(smem + 8192);

    const int tid = threadIdx.x;
    const int lane = tid & 63;
    const int w = tid >> 6;
    const int wr = w >> 1, wc = w & 1;

    const int nwg = gridDim.x;
    const int q = nwg >> 3;
    const int swz = (blockIdx.x & 7) * q + (blockIdx.x >> 3);
    const int by = swz / nbx, bx = swz - by * nbx;
    const int row0 = by * 128, col0 = bx * 128;

    f32x4 acc[4][4];
#pragma unroll
    for (int m = 0; m < 4; ++m)
#pragma unroll
        for (int n = 0; n < 4; ++n) acc[m][n] = (f32x4)(0.0f);

    int offs[2], rr[2], kk8[2];
#pragma unroll
    for (int c = 0; c < 2; ++c) {
        offs[c] = (w * 2 + c) * 1024 + lane * 16;
        rr[c] = offs[c] >> 6;
        kk8[c] = ((offs[c] >> 4) & 3) * 8;
    }

    for (int k0 = 0; k0 < K; k0 += 32) {
#pragma unroll
        for (int c = 0; c < 2; ++c) {
            const bf16_t* gA = A + (size_t)(row0 + rr[c]) * K + k0 + kk8[c];
            GLOAD_LDS16(gA, As + (w * 2 + c) * 512);
            const bf16_t* gB = BT + (size_t)(col0 + rr[c]) * K + k0 + kk8[c];
            GLOAD_LDS16(gB, Bs + (w * 2 + c) * 512);
        }
        __syncthreads();

        bf16x8 af[4], bfr[4];
#pragma unroll
        for (int m = 0; m < 4; ++m)
            af[m] = *(const bf16x8*)&As[(wr * 64 + m * 16 + (lane & 15)) * 32 + (lane >> 4) * 8];
#pragma unroll
        for (int n = 0; n < 4; ++n)
            bfr[n] = *(const bf16x8*)&Bs[(wc * 64 + n * 16 + (lane & 15)) * 32 + (lane >> 4) * 8];
#pragma unroll
        for (int m = 0; m < 4; ++m)
#pragma unroll
            for (int n = 0; n < 4; ++n)
                acc[m][n] = __builtin_amdgcn_mfma_f32_16x16x32_bf16(af[m], bfr[n], acc[m][n], 0, 0, 0);
        __syncthreads();
    }

    if (MODE == 0) {
        bf16_t* Cs = (bf16_t*)smem;           // [128 cols][pitch 136]
#pragma unroll
        for (int m = 0; m < 4; ++m)
#pragma unroll
            for (int n = 0; n < 4; ++n) {
                int cl = wc * 64 + n * 16 + (lane & 15);
                int rlb = wr * 64 + m * 16 + ((lane >> 4) << 2);
                float bb = bias[col0 + cl];
#pragma unroll
                for (int j = 0; j < 4; ++j)
                    Cs[cl * 136 + rlb + j] = f2bf(acc[m][n][j] + bb);
            }
        __syncthreads();
        int dl = tid >> 1, th = tid & 1;
        int cc = col0 + dl;
        int s = cc >> 10, d = cc & 1023;
        int b = row0 >> 12;
        int t0 = (row0 & 4095) + th * 64;
        uint4* dst = (uint4*)&((bf16_t*)outv)[((size_t)(s * 4 + b) * 1024 + d) * 4096 + t0];
        const uint4* src = (const uint4*)&Cs[dl * 136 + th * 64];
#pragma unroll
        for (int j = 0; j < 8; ++j) dst[j] = src[j];
    } else {
        float* CsF = (float*)smem;            // [128 cols][pitch 132]
#pragma unroll
        for (int m = 0; m < 4; ++m)
#pragma unroll
            for (int n = 0; n < 4; ++n) {
                int cl = wc * 64 + n * 16 + (lane & 15);
                int rlb = wr * 64 + m * 16 + ((lane >> 4) << 2);
                float bb = bias[col0 + cl];
#pragma unroll
                for (int j = 0; j < 4; ++j)
                    CsF[cl * 132 + rlb + j] = acc[m][n][j] + bb;
            }
        __syncthreads();
        int dl = tid >> 1, th = tid & 1;
        int cc = col0 + dl;
        uint4* dst = (uint4*)&((float*)outv)[(size_t)cc * 4096 + row0 + th * 64];
        const uint4* src = (const uint4*)&CsF[dl * 132 + th * 64];
#pragma unroll
        for (int j = 0; j < 16; ++j) dst[j] = src[j];
    }
}

// ---------------------------------------------------------------- radix-4 Stockham FFT, N=4096
// Derived by fusing two verified radix-2 Stockham stages:
//   read src[p + c*1024], p in [0,1024), m in {1,4,16,64,256,1024}, jm = p & ~(m-1), r = p - jm
//   D[4jm+r]    = (A+C)+(B+E)
//   D[4jm+r+m]  = W^jm  [(A-C) -/+ i(B-E)]   (fwd: -i, inv: +i)
//   D[4jm+r+2m] = W^2jm [(A+C)-(B+E)]
//   D[4jm+r+3m] = W^3jm [(A-C) +/- i(B-E)]
// Wq[x] = exp(-2*pi*i*x/4096), x in [0,1024) (jm < 1024 always). 6 stages, result back in A.
template <int INV>
__device__ void fft4096(float2* __restrict__ sA, float2* __restrict__ sB,
                        const float2* __restrict__ Wq) {
    const int tid = threadIdx.x;
    float2* src = sA;
    float2* dst = sB;
#pragma unroll
    for (int m = 1; m < 4096; m <<= 2) {
#pragma unroll
        for (int u = 0; u < 2; ++u) {
            int p = u * NT + tid;
            int r = p & (m - 1);
            int jm = p - r;
            float2 a = src[p], b = src[p + 1024], c = src[p + 2048], e = src[p + 3072];
            float2 t0 = cadd(a, c), t1 = csub(a, c), t2 = cadd(b, e), t3 = csub(b, e);
            float2 it3 = INV ? make_float2(-t3.y, t3.x) : make_float2(t3.y, -t3.x);
            float2 f0 = cadd(t0, t2);
            float2 f2 = csub(t0, t2);
            float2 f1 = cadd(t1, it3);
            float2 f3 = csub(t1, it3);
            float2 w1 = Wq[jm];
            if (INV) w1.y = -w1.y;
            float2 w2 = cmul(w1, w1);
            float2 w3 = cmul(w2, w1);
            int base = 4 * jm + r;
            if (m == 1) {   // contiguous: vectorize as 2x float4
                float2 g1 = cmul(w1, f1), g2 = cmul(w2, f2), g3 = cmul(w3, f3);
                ((float4*)dst)[base >> 1]       = make_float4(f0.x, f0.y, g1.x, g1.y);
                ((float4*)dst)[(base >> 1) + 1] = make_float4(g2.x, g2.y, g3.x, g3.y);
            } else {
                dst[base]         = f0;
                dst[base + m]     = cmul(w1, f1);
                dst[base + 2 * m] = cmul(w2, f2);
                dst[base + 3 * m] = cmul(w3, f3);
            }
        }
        __syncthreads();
        float2* t = src; src = dst; dst = t;
    }
}

__device__ __forceinline__ void init_twiddles4096(float2* Wq) {
    const int tid = threadIdx.x;
#pragma unroll
    for (int u = 0; u < 1024 / NT; ++u) {
        int j = u * NT + tid;
        float s, c;
        __sincosf((float)j * -1.5339807878856412e-3f, &s, &c);   // -2*pi/4096
        Wq[j] = make_float2(c, s);
    }
}

// spec accessors (half-spectrum rows of 4097 complex, f32 or bf16 pairs)
__device__ __forceinline__ float2 spec_load(const void* spec, int bf, size_t row, int k) {
    if (bf) {
        ushort2 h = ((const ushort2*)spec)[row * 4097 + k];
        return make_float2(bf2f(h.x), bf2f(h.y));
    }
    return ((const float2*)spec)[row * 4097 + k];
}
__device__ __forceinline__ void spec_store(void* spec, int bf, size_t row, int k, float2 v) {
    if (bf) ((ushort2*)spec)[row * 4097 + k] = make_ushort2(f2bf(v.x), f2bf(v.y));
    else    ((float2*)spec)[row * 4097 + k] = v;
}

// ---------------------------------------------------------------- filter spectra (packed real FFT)
// fT row e = i*1024+d (f32, 4096 samples, implicit zero pad to 8192)
// F[k] = DFT_8192(f_pad)[k], k in [0,4096], via 4096-pt packed FFT + untangle.
__global__ __launch_bounds__(NT) void filter_fft_kernel(const float* __restrict__ fT,
                                                        void* __restrict__ specv,
                                                        int spec_bf16) {
    __shared__ __align__(16) float2 sA[4096];
    __shared__ __align__(16) float2 sB[4096];
    __shared__ float2 Wq[1024];
    const int tid = threadIdx.x;
    const size_t row = blockIdx.x;          // i*1024 + d
    init_twiddles4096(Wq);
    const float2* f2p = (const float2*)&fT[row * T_LEN];
#pragma unroll
    for (int u = 0; u < 4096 / NT; ++u) {
        int n = u * NT + tid;
        sA[n] = (n < 2048) ? f2p[n] : make_float2(0.0f, 0.0f);
    }
    __syncthreads();
    fft4096<0>(sA, sB, Wq);
    // untangle: F[k] = Ye + W_8192^k * Yo ; F[4096-k] = conj(Ye - W^k Yo)
#pragma unroll
    for (int u = 0; u < 2048 / NT; ++u) {
        int s = u * NT + tid;
        if (s < 2047) {
            int k = s + 1, nk = 4096 - k;
            float2 Zk = sA[k], Zn = sA[nk];
            float2 Ye = make_float2(0.5f * (Zk.x + Zn.x), 0.5f * (Zk.y - Zn.y));
            float2 Yo = make_float2(0.5f * (Zk.y + Zn.y), -0.5f * (Zk.x - Zn.x));
            float ss, cc;
            __sincosf((float)k * -7.669903939428206e-4f, &ss, &cc);  // -pi/4096
            float2 w = make_float2(cc, ss);
            float2 wYo = cmul(w, Yo);
            spec_store(specv, spec_bf16, row, k, cadd(Ye, wYo));
            spec_store(specv, spec_bf16, row, nk, conjf2(csub(Ye, wYo)));
        }
    }
    if (tid == 0) {
        float2 Z0 = sA[0];
        spec_store(specv, spec_bf16, row, 0,    make_float2(Z0.x + Z0.y, 0.0f));
        spec_store(specv, spec_bf16, row, 4096, make_float2(Z0.x - Z0.y, 0.0f));
        spec_store(specv, spec_bf16, row, 2048, conjf2(sA[2048]));
    }
}

// ---------------------------------------------------------------- fused 3-stage conv (packed real FFT)
// xpT bf16: ((s*4+b)*1024+d)*4096 + t ; writes yT bf16 (b*1024+d)*4096 + t
__global__ __launch_bounds__(NT) void conv_kernel(const bf16_t* __restrict__ xpT,
                                                  const void* __restrict__ specv,
                                                  int spec_bf16,
                                                  bf16_t* __restrict__ yT) {
    __shared__ __align__(16) float2 sA[4096];
    __shared__ __align__(16) float2 sB[4096];
    __shared__ float2 Wq[1024];
    const int tid = threadIdx.x;
    const int bid = blockIdx.x;             // b*1024 + d
    const int b = bid >> 10;
    const int d = bid & 1023;
    init_twiddles4096(Wq);

    // pack y0 = xp[:, :, 0, :]: z[n] = y[2n] + i*y[2n+1], zero top half
    const ushort2* y0 = (const ushort2*)&xpT[((size_t)b * 1024 + d) * T_LEN];
#pragma unroll
    for (int u = 0; u < 4096 / NT; ++u) {
        int n = u * NT + tid;
        if (n < 2048) {
            ushort2 h = y0[n];
            sA[n] = make_float2(bf2f(h.x), bf2f(h.y));
        } else {
            sA[n] = make_float2(0.0f, 0.0f);
        }
    }
    __syncthreads();

    const float scale = 1.0f / 4096.0f;
    for (int st = 0; st < N_STAGES; ++st) {
        fft4096<0>(sA, sB, Wq);                       // forward, result in sA
        const size_t row = (size_t)st * 1024 + d;
        // untangle -> Y, multiply by F, repack -> inverse-FFT input (in place, pairwise)
#pragma unroll
        for (int u = 0; u < 2048 / NT; ++u) {
            int s = u * NT + tid;
            if (s < 2047) {
                int k = s + 1, nk = 4096 - k;
                float2 Zk = sA[k], Zn = sA[nk];
                float2 Ye = make_float2(0.5f * (Zk.x + Zn.x), 0.5f * (Zk.y - Zn.y));
                float2 Yo = make_float2(0.5f * (Zk.y + Zn.y), -0.5f * (Zk.x - Zn.x));
                float ss, cc;
                __sincosf((float)k * -7.669903939428206e-4f, &ss, &cc);  // -pi/4096
                float2 w = make_float2(cc, ss);
                float2 wYo = cmul(w, Yo);
                float2 Yk = cadd(Ye, wYo);
                float2 Ynk = conjf2(csub(Ye, wYo));
                float2 Fk = spec_load(specv, spec_bf16, row, k);
                float2 Fn = spec_load(specv, spec_bf16, row, nk);
                float2 Hk = cmul(Yk, Fk);
                float2 Hn = cmul(Ynk, Fn);
                float2 He = make_float2(0.5f * (Hk.x + Hn.x), 0.5f * (Hk.y - Hn.y));
                float2 Hd = make_float2(0.5f * (Hk.x - Hn.x), 0.5f * (Hk.y + Hn.y));
                float2 Ho = cmul(conjf2(w), Hd);
                sA[k]  = make_float2(He.x - Ho.y, He.y + Ho.x);
                sA[nk] = make_float2(He.x + Ho.y, Ho.x - He.y);
            }
        }
        if (tid == 0) {
            float2 Z0 = sA[0];
            float Y0 = Z0.x + Z0.y, YN = Z0.x - Z0.y;
            float2 F0 = spec_load(specv, spec_bf16, row, 0);
            float2 FN = spec_load(specv, spec_bf16, row, 4096);
            float2 H0 = make_float2(Y0 * F0.x, Y0 * F0.y);
            float2 HN = make_float2(YN * FN.x, YN * FN.y);
            float2 He0 = make_float2(0.5f * (H0.x + HN.x), 0.5f * (H0.y + HN.y));
            float2 Ho0 = make_float2(0.5f * (H0.x - HN.x), 0.5f * (H0.y - HN.y));
            sA[0] = make_float2(He0.x - Ho0.y, He0.y + Ho0.x);
            float2 H2 = cmul(conjf2(sA[2048]), spec_load(specv, spec_bf16, row, 2048));
            sA[2048] = conjf2(H2);
        }
        __syncthreads();
        fft4096<1>(sA, sB, Wq);                       // inverse (unnormalized), result in sA

        const ushort2* g = (const ushort2*)&xpT[((size_t)((st + 1) * 4 + b) * 1024 + d) * T_LEN];
        if (st < N_STAGES - 1) {
#pragma unroll
            for (int u = 0; u < 4096 / NT; ++u) {
                int n = u * NT + tid;
                if (n < 2048) {
                    ushort2 h = g[n];
                    float2 v = sA[n];
                    sA[n] = make_float2(v.x * scale * bf2f(h.x), v.y * scale * bf2f(h.y));
                } else {
                    sA[n] = make_float2(0.0f, 0.0f);
                }
            }
            __syncthreads();
        } else {
            ushort2* yrow = (ushort2*)&yT[((size_t)b * 1024 + d) * T_LEN];
#pragma unroll
            for (int u = 0; u < 2048 / NT; ++u) {
                int n = u * NT + tid;
                ushort2 h = g[n];
                float2 v = sA[n];
                yrow[n] = make_ushort2(f2bf(v.x * scale * bf2f(h.x)),
                                       f2bf(v.y * scale * bf2f(h.y)));
            }
        }
    }
}

// ---------------------------------------------------------------- yT (B,D,T) bf16 -> out (B,T,D) f32
__global__ __launch_bounds__(256) void transpose_out(const bf16_t* __restrict__ yT,
                                                     float* __restrict__ out) {
    __shared__ float tile[32][33];
    const int tb = blockIdx.z;
    const int t0 = blockIdx.x * 32;
    const int d0 = blockIdx.y * 32;
    const int tx = threadIdx.x & 31;
    const int ty = threadIdx.x >> 5;
    for (int i = ty; i < 32; i += 8)
        tile[i][tx] = bf2f(yT[((size_t)tb * 1024 + d0 + i) * 4096 + t0 + tx]);
    __syncthreads();
    for (int i = ty; i < 32; i += 8)
        out[((size_t)tb * 4096 + t0 + i) * 1024 + d0 + tx] = tile[tx][i];
}

// ---------------------------------------------------------------- launch
extern "C" void kernel_launch(void* const* d_in, const int* in_sizes, int n_in,
                              void* d_out, int out_size, void* d_ws, size_t ws_size,
                              hipStream_t stream) {
    const float* X   = (const float*)d_in[0];
    const float* Wp  = (const float*)d_in[1];
    const float* bp  = (const float*)d_in[2];
    const float* Wf  = (const float*)d_in[3];
    const float* bfv = (const float*)d_in[4];
    float* out = (float*)d_out;
    char* ws = (char*)d_ws;

    // workspace:
    //  [0, 128Mi)   xpT bf16. Pre-GEMM2 staging inside: posbf [0,8Mi), WfT [16Mi,22Mi),
    //               fT f32 [32Mi,80Mi).
    //  [128Mi, +spec)  filter spectra (f32 pairs if ws allows, else bf16 pairs)
    //  [.., +32Mi)     Xbf (bf16 X) -- reused as yT (bf16 conv output) after GEMM2
    //  [.., +8Mi)      WpT (bf16 transposed Wp)
    const size_t XPT_BYTES  = (size_t)134217728;
    const size_t SPEC_F32_B = (size_t)3 * 1024 * 4097 * 8;
    const size_t SPEC_BF_B  = (size_t)3 * 1024 * 4097 * 4;
    const size_t XBF_BYTES  = (size_t)33554432;
    const size_t WPT_BYTES  = (size_t)8388608;

    bf16_t* xpT   = (bf16_t*)ws;
    bf16_t* posbf = (bf16_t*)ws;
    bf16_t* WfT   = (bf16_t*)(ws + 16777216);
    float*  fT    = (float*)(ws + 33554432);
    void*   spec  = (void*)(ws + XPT_BYTES);

    int spec_bf16;
    size_t spec_bytes;
    if (ws_size >= XPT_BYTES + SPEC_F32_B + XBF_BYTES + WPT_BYTES) {
        spec_bf16 = 0; spec_bytes = SPEC_F32_B;
    } else {
        spec_bf16 = 1; spec_bytes = SPEC_BF_B;
    }
    bf16_t* Xbf = (bf16_t*)(ws + XPT_BYTES + spec_bytes);
    bf16_t* WpT = (bf16_t*)(ws + XPT_BYTES + spec_bytes + XBF_BYTES);
    bf16_t* yT  = Xbf;   // reuse after GEMM2 consumes Xbf

    // 1. positional encoding (bf16)
    pos_kernel<<<(T_LEN * D_DIM) / 256, 256, 0, stream>>>(posbf);

    // 2. WfT = transpose(Wf); f = pos @ Wf + bf -> fT f32 [(i*D+d)][t]
    transpose_to_bf16<<<dim3(3072 / 32, 1024 / 32), 256, 0, stream>>>(Wf, WfT, 1024, 3072);
    mfma_gemm<1><<<768, 256, 0, stream>>>(posbf, WfT, bfv, fT, 4096, 3072, 1024, 24);

    // 3. filter spectra (packed real FFT)
    filter_fft_kernel<<<N_STAGES * D_DIM, NT, 0, stream>>>(fT, spec, spec_bf16);

    // 4. Xbf, WpT ; xp = X @ Wp + bp -> xpT bf16
    f32_to_bf16_kernel<<<8192, 256, 0, stream>>>(X, Xbf, 2097152);
    transpose_to_bf16<<<dim3(4096 / 32, 1024 / 32), 256, 0, stream>>>(Wp, WpT, 1024, 4096);
    mfma_gemm<0><<<4096, 256, 0, stream>>>(Xbf, WpT, bp, xpT, 16384, 4096, 1024, 32);

    // 5. fused 3-stage FFT conv + gating -> yT (bf16, coalesced)
    conv_kernel<<<B_DIM * D_DIM, NT, 0, stream>>>(xpT, spec, spec_bf16, yT);

    // 6. transpose to output layout (B,T,D) f32
    transpose_out<<<dim3(4096 / 32, 1024 / 32, B_DIM), 256, 0, stream>>>(yT, out);
}